// Round 8
// baseline (153.362 us; speedup 1.0000x reference)
//
#include <hip/hip_runtime.h>
#include <hip/hip_bf16.h>

typedef __attribute__((ext_vector_type(4))) float  floatx4;
typedef __attribute__((ext_vector_type(2))) float  floatx2;
typedef __attribute__((ext_vector_type(8))) __bf16 bf16x8;

#define FP8_MAX 448.0f

// HW OCP e4m3fn round-trip (RNE), matches ml_dtypes float8_e4m3fn for |v|<=448
__device__ __forceinline__ floatx2 fp8_qdq2(float a, float b) {
    int p = __builtin_amdgcn_cvt_pk_fp8_f32(a, b, 0, false);
    return __builtin_amdgcn_cvt_pk_f32_fp8(p, false);
}

__device__ __forceinline__ unsigned int f2bf(float f) {
    union { __hip_bfloat16 h; unsigned short u; } cv;
    cv.h = __float2bfloat16(f);
    return (unsigned int)cv.u;
}

__device__ __forceinline__ void async_copy16(void* lds, const void* g) {
    __builtin_amdgcn_global_load_lds(
        (const __attribute__((address_space(1))) unsigned int*)g,
        (__attribute__((address_space(3))) unsigned int*)lds, 16, 0, 0);
}

// ---------------------------------------------------------------------------
// Kernel 1: dequantize W [D=512][F=512] (quant blocks of 128 along F),
//           write transposed bf16 Wt [F=512][D=512].
__global__ void wdq_kernel(const float* __restrict__ W,
                           __hip_bfloat16* __restrict__ Wt) {
    const int D = 512, F = 512;
    int d = blockIdx.x;
    int t = threadIdx.x;
    float4 v = *reinterpret_cast<const float4*>(W + (size_t)d * F + t * 4);
    float am = fmaxf(fmaxf(fabsf(v.x), fabsf(v.y)), fmaxf(fabsf(v.z), fabsf(v.w)));
#pragma unroll
    for (int s = 16; s >= 1; s >>= 1) am = fmaxf(am, __shfl_xor(am, s));
    float scale = fmaxf(am, 1e-4f) / FP8_MAX;
    floatx2 d01 = fp8_qdq2(v.x / scale, v.y / scale);
    floatx2 d23 = fp8_qdq2(v.z / scale, v.w / scale);
    int f0 = t * 4;
    Wt[(size_t)(f0 + 0) * D + d] = __float2bfloat16(d01[0] * scale);
    Wt[(size_t)(f0 + 1) * D + d] = __float2bfloat16(d01[1] * scale);
    Wt[(size_t)(f0 + 2) * D + d] = __float2bfloat16(d23[0] * scale);
    Wt[(size_t)(f0 + 3) * D + d] = __float2bfloat16(d23[1] * scale);
}

// ---------------------------------------------------------------------------
// Kernel 2 (fused, reg-quant A, LDS = Bs only):
// BM=64, BN=128, 256 thr = 4 waves (2M x 2N; wave tile 32x64, acc[2][4]).
// A path: each lane loads ITS MFMA A-fragment source f32 straight from HBM
//   (lane l, row wm*32+mi*16+(l&15), k-octets (l>>4)*8+32j within the 128-k
//   quant block), partial amax, shfl_xor(16,32) -> blockwise scale, fp8
//   round-trip, bf16 frags af[2][4] in REGISTERS. No A LDS, no lgkm chains.
// B path: Bs[2][128 f][64 k] bf16 double-buffered via global_load_lds
//   (linear dest + pre-swizzled source, slot^=f&7; read with same XOR).
// One __syncthreads per K-step; 32 KB LDS -> 4 blocks/CU so the barrier
// vmcnt drain is hidden by the other resident blocks (m97/m114 ethos).
__global__ __launch_bounds__(256, 4) void fused_gemm(
        const float* __restrict__ X,             // [M][512] f32
        const __hip_bfloat16* __restrict__ Wt,   // [512 f][512 k] bf16
        const float* __restrict__ bias,          // [512]
        float* __restrict__ C, int M) {
    const int K = 512, N = 512;
    __shared__ char Bs[2][16384];   // [128 f][8 slot16B] bf16, slot ^= f&7

    // XCD-chunked bijective swizzle: the 4 tN tiles of each mg are adjacent
    // within one XCD's chunk -> X panel L2/L3 reuse (verified rounds 3/7).
    int bx   = blockIdx.x;
    int nwg  = gridDim.x;                 // 4096 (multiple of 8)
    int cpx  = nwg >> 3;
    int tile = (bx & 7) * cpx + (bx >> 3);
    int tN   = tile & 3;                  // N-panel of 128
    int mg   = tile >> 2;                 // M-tile of 64 rows

    int tid = threadIdx.x, wid = tid >> 6, lane = tid & 63;
    int wm = wid >> 1, wn = wid & 1;      // wave grid 2(M) x 2(N)
    int lr = lane & 15, lg = lane >> 4;   // frag row-in-16, k-octet group

    const float* Xb = X + (size_t)(mg * 64) * K;
    const __hip_bfloat16* Wb = Wt + (size_t)tN * 128 * K;
    float* Cb = C + (size_t)(mg * 64) * N + tN * 128;

    floatx4 acc[2][4] = {};
    bf16x8  af[2][4];     // A fragments for current 128-k quant block

    // Bs stage: 16 x 1KB chunks; 4 per wave. Linear LDS dest, source
    // pre-swizzled so that read-side XOR lands on the right bytes.
    auto issueBs = [&](int buf, int step) {
        const char* base = (const char*)Wb + step * 128;   // k0*2 bytes
#pragma unroll
        for (int cc = 0; cc < 4; ++cc) {
            int c  = wid * 4 + cc;
            int rr = c * 8 + (lane >> 3);          // f-row
            int d  = lane & 7;                     // 16B slot
            async_copy16(Bs[buf] + c * 1024,
                         base + (size_t)rr * (K * 2) + ((d ^ (rr & 7)) << 4));
        }
    };
    // Quantize quant-block kb (k = kb*128 .. +128) of this thread's 2 rows
    // directly into af[][]. Exact reference scale: max(amax,1e-4)/448.
    auto quantA = [&](int kb) {
#pragma unroll
        for (int mi = 0; mi < 2; ++mi) {
            const float* src = Xb + (size_t)(wm * 32 + mi * 16 + lr) * K
                                  + kb * 128 + lg * 8;
            float4 xv[8];
#pragma unroll
            for (int j = 0; j < 4; ++j) {
                xv[2*j]   = *reinterpret_cast<const float4*>(src + 32 * j);
                xv[2*j+1] = *reinterpret_cast<const float4*>(src + 32 * j + 4);
            }
            float am = 0.f;
#pragma unroll
            for (int j = 0; j < 8; ++j)
                am = fmaxf(am, fmaxf(fmaxf(fabsf(xv[j].x), fabsf(xv[j].y)),
                                     fmaxf(fabsf(xv[j].z), fabsf(xv[j].w))));
            am = fmaxf(am, __shfl_xor(am, 16));
            am = fmaxf(am, __shfl_xor(am, 32));
            am = fmaxf(am, 1e-4f);
            float scale = am / FP8_MAX;
            float inv   = FP8_MAX / am;
#pragma unroll
            for (int j = 0; j < 4; ++j) {
                floatx2 a0 = fp8_qdq2(xv[2*j].x*inv,   xv[2*j].y*inv);
                floatx2 a1 = fp8_qdq2(xv[2*j].z*inv,   xv[2*j].w*inv);
                floatx2 a2 = fp8_qdq2(xv[2*j+1].x*inv, xv[2*j+1].y*inv);
                floatx2 a3 = fp8_qdq2(xv[2*j+1].z*inv, xv[2*j+1].w*inv);
                uint4 o;
                o.x = f2bf(a0[0]*scale) | (f2bf(a0[1]*scale) << 16);
                o.y = f2bf(a1[0]*scale) | (f2bf(a1[1]*scale) << 16);
                o.z = f2bf(a2[0]*scale) | (f2bf(a2[1]*scale) << 16);
                o.w = f2bf(a3[0]*scale) | (f2bf(a3[1]*scale) << 16);
                union { uint4 u; bf16x8 b; } cv; cv.u = o;
                af[mi][j] = cv.b;
            }
        }
    };
    auto mfmaStep = [&](int buf, int h) {      // h = k-half within quant block
#pragma unroll
        for (int ks = 0; ks < 2; ++ks) {
            int sl = ks * 4 + lg;
            bf16x8 b[4];
#pragma unroll
            for (int ni = 0; ni < 4; ++ni) {
                int f = wn * 64 + ni * 16 + lr;
                b[ni] = *reinterpret_cast<const bf16x8*>(
                    Bs[buf] + f * 128 + ((sl ^ (f & 7)) << 4));
            }
#pragma unroll
            for (int mi = 0; mi < 2; ++mi)
#pragma unroll
                for (int ni = 0; ni < 4; ++ni)
                    acc[mi][ni] = __builtin_amdgcn_mfma_f32_16x16x32_bf16(
                        af[mi][h * 2 + ks], b[ni], acc[mi][ni], 0, 0, 0);
        }
    };

    // ---- prologue: Bs step0 DMA overlaps quant of kb0 --------------------
    issueBs(0, 0);
    quantA(0);
    __syncthreads();

    // ---- main: 8 K-steps of 64, one barrier each --------------------------
#pragma unroll
    for (int s = 0; s < 8; ++s) {
        int cur = s & 1, nxt = cur ^ 1;
        if (s < 7) issueBs(nxt, s + 1);
        if (s && (s & 1) == 0) quantA(s >> 1);   // new quant block (af regs)
        mfmaStep(cur, s & 1);
        if (s < 7) __syncthreads();
    }

    // ---- epilogue: C/D layout col=lane&15, row=(lane>>4)*4+e --------------
#pragma unroll
    for (int ni = 0; ni < 4; ++ni) {
        int col = wn * 64 + ni * 16 + lr;
        float bv = bias[tN * 128 + col];
#pragma unroll
        for (int mi = 0; mi < 2; ++mi) {
            int r0 = wm * 32 + mi * 16 + lg * 4;
#pragma unroll
            for (int e = 0; e < 4; ++e)
                Cb[(size_t)(r0 + e) * N + col] = acc[mi][ni][e] + bv;
        }
    }
}

// ---------------------------------------------------------------------------
extern "C" void kernel_launch(void* const* d_in, const int* in_sizes, int n_in,
                              void* d_out, int out_size, void* d_ws, size_t ws_size,
                              hipStream_t stream) {
    const float* X    = (const float*)d_in[0];
    const float* W    = (const float*)d_in[1];
    const float* bias = (const float*)d_in[2];
    const int K = 512;
    const int M = in_sizes[0] / K;   // 65536

    __hip_bfloat16* Wt = (__hip_bfloat16*)d_ws;   // 512*512*2 = 512 KB

    wdq_kernel<<<dim3(512), dim3(128), 0, stream>>>(W, Wt);
    fused_gemm<<<dim3((M / 64) * 4), dim3(256), 0, stream>>>(
        X, Wt, bias, (float*)d_out, M);
}

// Round 9
// 99.384 us; speedup vs baseline: 1.5431x; 1.5431x over previous
//
#include <hip/hip_runtime.h>
#include <hip/hip_bf16.h>

typedef __attribute__((ext_vector_type(4))) float  floatx4;
typedef __attribute__((ext_vector_type(2))) float  floatx2;
typedef __attribute__((ext_vector_type(8))) __bf16 bf16x8;

#define FP8_MAX 448.0f

// HW OCP e4m3fn round-trip (RNE), matches ml_dtypes float8_e4m3fn for |v|<=448
__device__ __forceinline__ floatx2 fp8_qdq2(float a, float b) {
    int p = __builtin_amdgcn_cvt_pk_fp8_f32(a, b, 0, false);
    return __builtin_amdgcn_cvt_pk_f32_fp8(p, false);
}

__device__ __forceinline__ unsigned int f2bf(float f) {
    union { __hip_bfloat16 h; unsigned short u; } cv;
    cv.h = __float2bfloat16(f);
    return (unsigned int)cv.u;
}

__device__ __forceinline__ void async_copy16(void* lds, const void* g) {
    __builtin_amdgcn_global_load_lds(
        (const __attribute__((address_space(1))) unsigned int*)g,
        (__attribute__((address_space(3))) unsigned int*)lds, 16, 0, 0);
}

// ---------------------------------------------------------------------------
// Kernel 1: dequantize W [D=512][F=512] (quant blocks of 128 along F),
//           write transposed bf16 Wt [F=512][D=512].
__global__ void wdq_kernel(const float* __restrict__ W,
                           __hip_bfloat16* __restrict__ Wt) {
    const int D = 512, F = 512;
    int d = blockIdx.x;
    int t = threadIdx.x;
    float4 v = *reinterpret_cast<const float4*>(W + (size_t)d * F + t * 4);
    float am = fmaxf(fmaxf(fabsf(v.x), fabsf(v.y)), fmaxf(fabsf(v.z), fabsf(v.w)));
#pragma unroll
    for (int s = 16; s >= 1; s >>= 1) am = fmaxf(am, __shfl_xor(am, s));
    float scale = fmaxf(am, 1e-4f) / FP8_MAX;
    floatx2 d01 = fp8_qdq2(v.x / scale, v.y / scale);
    floatx2 d23 = fp8_qdq2(v.z / scale, v.w / scale);
    int f0 = t * 4;
    Wt[(size_t)(f0 + 0) * D + d] = __float2bfloat16(d01[0] * scale);
    Wt[(size_t)(f0 + 1) * D + d] = __float2bfloat16(d01[1] * scale);
    Wt[(size_t)(f0 + 2) * D + d] = __float2bfloat16(d23[0] * scale);
    Wt[(size_t)(f0 + 3) * D + d] = __float2bfloat16(d23[1] * scale);
}

// ---------------------------------------------------------------------------
// Kernel 2: streaming X quant-dequant f32 -> bf16 (quant blocks 128 along K).
// 2 rows/block, 256 thr; thread = 4 consecutive f32 (float4 in, uint2 out).
// Quant block = 32 consecutive lanes; shfl_xor{1,2,4,8,16} stays in 32-half.
__global__ void xqdq_kernel(const float* __restrict__ X,
                            __hip_bfloat16* __restrict__ Xdq) {
    int tid = threadIdx.x;
    size_t row = (size_t)blockIdx.x * 2 + (tid >> 7);
    int cg = tid & 127;                   // col group: 4 f32 each
    const float4 v = *reinterpret_cast<const float4*>(X + row * 512 + cg * 4);
    float am = fmaxf(fmaxf(fabsf(v.x), fabsf(v.y)), fmaxf(fabsf(v.z), fabsf(v.w)));
    am = fmaxf(am, __shfl_xor(am, 1));
    am = fmaxf(am, __shfl_xor(am, 2));
    am = fmaxf(am, __shfl_xor(am, 4));
    am = fmaxf(am, __shfl_xor(am, 8));
    am = fmaxf(am, __shfl_xor(am, 16));
    am = fmaxf(am, 1e-4f);
    float scale = am / FP8_MAX;           // exact reference scale (IEEE div)
    float inv   = FP8_MAX / am;
    floatx2 d01 = fp8_qdq2(v.x * inv, v.y * inv);
    floatx2 d23 = fp8_qdq2(v.z * inv, v.w * inv);
    uint2 o;
    o.x = f2bf(d01[0] * scale) | (f2bf(d01[1] * scale) << 16);
    o.y = f2bf(d23[0] * scale) | (f2bf(d23[1] * scale) << 16);
    *reinterpret_cast<uint2*>(Xdq + row * 512 + cg * 4) = o;
}

// ---------------------------------------------------------------------------
// Kernel 3: bf16 GEMM with triple-buffered LDS + counted vmcnt.
// BM=128, BN=256, BK=64; 512 thr = 8 waves (2M x 4N), wave tile 64x64,
// acc 4x4 frags, 32 MFMA/wave/iter. LDS: 3 bufs x (A 16KB + B 32KB) = 144KB.
// Iter t reads buf[t%3], stages tile t+2 into buf[(t+2)%3] (nobody reads it
// -> no same-buffer hazard). Boundary: {vmcnt(6); s_barrier; sched_barrier}.
// vmcnt derivation: prev boundary left tile t+1's 6 loads in flight; iter t
// issues 6 more (tile t+2); drain to 6 => tile t+1 landed, t+2 floats.
// All main-loop VMEM is wave-uniform global_load_lds -> FIFO count exact.
// XOR slot swizzle both-sides (slot ^= row&7): 0 conflicts (rounds 3/4/7/8).
__global__ __launch_bounds__(512, 1) void gemm8(
        const __hip_bfloat16* __restrict__ Xdq,  // [M][512] bf16
        const __hip_bfloat16* __restrict__ Wt,   // [512 f][512 k] bf16
        const float* __restrict__ bias,          // [512]
        float* __restrict__ C, int M) {
    const int K = 512, N = 512;
    __shared__ char lds[3][49152];   // per buf: A [128r][8 slot16B] then B [256f][8 slot16B]

    // XCD-chunked bijective swizzle (grid 1024 % 8 == 0): both tn panels of
    // a tm adjacent on one XCD -> A-panel L2 reuse.
    int bx   = blockIdx.x;
    int tile = (bx & 7) * (gridDim.x >> 3) + (bx >> 3);
    int tn   = tile & 1;             // N-panel of 256
    int tm   = tile >> 1;            // M-tile of 128 rows

    int tid = threadIdx.x, wid = tid >> 6, lane = tid & 63;
    int wm = wid >> 2, wn = wid & 3; // wave grid 2(M) x 4(N)
    int lr = lane & 15, lg = lane >> 4;

    const char* Abase = (const char*)(Xdq + (size_t)tm * 128 * K);
    const char* Bbase = (const char*)(Wt + (size_t)tn * 256 * K);
    float* Cb = C + (size_t)tm * 128 * N + tn * 256;

    floatx4 acc[4][4] = {};

    // stage tile t (k = t*64..) into buf: A 2 + B 4 gload_lds per thread.
    auto stage = [&](int buf, int t) {
        int kb = t * 128;                        // byte offset of k-slice
#pragma unroll
        for (int i = 0; i < 2; ++i) {            // A: 16 chunks of 1KB
            int c = wid * 2 + i;
            int r = c * 8 + (lane >> 3);         // row in [0,128)
            int s = lane & 7;
            async_copy16(lds[buf] + c * 1024,
                         Abase + (size_t)r * 1024 + kb + ((s ^ (r & 7)) << 4));
        }
#pragma unroll
        for (int i = 0; i < 4; ++i) {            // B: 32 chunks of 1KB
            int c = wid * 4 + i;
            int f = c * 8 + (lane >> 3);         // f in [0,256)
            int s = lane & 7;
            async_copy16(lds[buf] + 16384 + c * 1024,
                         Bbase + (size_t)f * 1024 + kb + ((s ^ (f & 7)) << 4));
        }
    };

    // ---- prologue: bias first (drained by first vmcnt), then 2 tiles ----
    float bv[4];
#pragma unroll
    for (int ni = 0; ni < 4; ++ni)
        bv[ni] = bias[tn * 256 + wn * 64 + ni * 16 + lr];
    stage(0, 0);
    stage(1, 1);
    asm volatile("s_waitcnt vmcnt(6)" ::: "memory");   // bias+tile0 done
    __builtin_amdgcn_s_barrier();
    __builtin_amdgcn_sched_barrier(0);

    // ---- main: 8 iters of BK=64, one barrier each ----
#pragma unroll
    for (int t = 0; t < 8; ++t) {
        const char* Ab = lds[t % 3];
        const char* Bb = lds[t % 3] + 16384;
        if (t < 6) stage((t + 2) % 3, t + 2);
        __builtin_amdgcn_s_setprio(1);
#pragma unroll
        for (int ks = 0; ks < 2; ++ks) {
            int q = (ks << 2) | lg;              // k-chunk 0..7
            bf16x8 a[4], b[4];
#pragma unroll
            for (int mi = 0; mi < 4; ++mi) {
                int r = wm * 64 + mi * 16 + lr;
                a[mi] = *reinterpret_cast<const bf16x8*>(
                    Ab + r * 128 + ((q ^ (r & 7)) << 4));
            }
#pragma unroll
            for (int ni = 0; ni < 4; ++ni) {
                int f = wn * 64 + ni * 16 + lr;
                b[ni] = *reinterpret_cast<const bf16x8*>(
                    Bb + f * 128 + ((q ^ (f & 7)) << 4));
            }
#pragma unroll
            for (int mi = 0; mi < 4; ++mi)
#pragma unroll
                for (int ni = 0; ni < 4; ++ni)
                    acc[mi][ni] = __builtin_amdgcn_mfma_f32_16x16x32_bf16(
                        a[mi], b[ni], acc[mi][ni], 0, 0, 0);
        }
        __builtin_amdgcn_s_setprio(0);
        if (t < 7) {
            if (t < 6) asm volatile("s_waitcnt vmcnt(6)" ::: "memory");
            else       asm volatile("s_waitcnt vmcnt(0)" ::: "memory");
            __builtin_amdgcn_s_barrier();
            __builtin_amdgcn_sched_barrier(0);
        }
    }

    // ---- epilogue: C/D layout col=lane&15, row=(lane>>4)*4+e ----
#pragma unroll
    for (int ni = 0; ni < 4; ++ni) {
        int col = wn * 64 + ni * 16 + lr;
#pragma unroll
        for (int mi = 0; mi < 4; ++mi) {
            int r0 = wm * 64 + mi * 16 + lg * 4;
#pragma unroll
            for (int e = 0; e < 4; ++e)
                Cb[(size_t)(r0 + e) * N + col] = acc[mi][ni][e] + bv[ni];
        }
    }
}

// ---------------------------------------------------------------------------
extern "C" void kernel_launch(void* const* d_in, const int* in_sizes, int n_in,
                              void* d_out, int out_size, void* d_ws, size_t ws_size,
                              hipStream_t stream) {
    const float* X    = (const float*)d_in[0];
    const float* W    = (const float*)d_in[1];
    const float* bias = (const float*)d_in[2];
    const int K = 512;
    const int M = in_sizes[0] / K;   // 65536

    __hip_bfloat16* Wt  = (__hip_bfloat16*)d_ws;      // 512 KB
    __hip_bfloat16* Xdq = Wt + 512 * 512;             // 64 MB

    wdq_kernel<<<dim3(512), dim3(128), 0, stream>>>(W, Wt);
    xqdq_kernel<<<dim3(M / 2), dim3(256), 0, stream>>>(X, Xdq);
    gemm8<<<dim3((M / 128) * 2), dim3(512), 0, stream>>>(
        Xdq, Wt, bias, (float*)d_out, M);
}

// Round 10
// 96.880 us; speedup vs baseline: 1.5830x; 1.0258x over previous
//
#include <hip/hip_runtime.h>
#include <hip/hip_bf16.h>

typedef __attribute__((ext_vector_type(4))) float  floatx4;
typedef __attribute__((ext_vector_type(2))) float  floatx2;
typedef __attribute__((ext_vector_type(8))) __bf16 bf16x8;

#define FP8_MAX 448.0f

// HW OCP e4m3fn round-trip (RNE), matches ml_dtypes float8_e4m3fn for |v|<=448
__device__ __forceinline__ floatx2 fp8_qdq2(float a, float b) {
    int p = __builtin_amdgcn_cvt_pk_fp8_f32(a, b, 0, false);
    return __builtin_amdgcn_cvt_pk_f32_fp8(p, false);
}

__device__ __forceinline__ unsigned int f2bf(float f) {
    union { __hip_bfloat16 h; unsigned short u; } cv;
    cv.h = __float2bfloat16(f);
    return (unsigned int)cv.u;
}

__device__ __forceinline__ void async_copy16(void* lds, const void* g) {
    __builtin_amdgcn_global_load_lds(
        (const __attribute__((address_space(1))) unsigned int*)g,
        (__attribute__((address_space(3))) unsigned int*)lds, 16, 0, 0);
}

// ---------------------------------------------------------------------------
// Kernel 1: dequantize W [D=512][F=512] (quant blocks of 128 along F),
//           write transposed bf16 Wt [F=512][D=512].
__global__ void wdq_kernel(const float* __restrict__ W,
                           __hip_bfloat16* __restrict__ Wt) {
    const int D = 512, F = 512;
    int d = blockIdx.x;
    int t = threadIdx.x;
    float4 v = *reinterpret_cast<const float4*>(W + (size_t)d * F + t * 4);
    float am = fmaxf(fmaxf(fabsf(v.x), fabsf(v.y)), fmaxf(fabsf(v.z), fabsf(v.w)));
#pragma unroll
    for (int s = 16; s >= 1; s >>= 1) am = fmaxf(am, __shfl_xor(am, s));
    float scale = fmaxf(am, 1e-4f) / FP8_MAX;
    floatx2 d01 = fp8_qdq2(v.x / scale, v.y / scale);
    floatx2 d23 = fp8_qdq2(v.z / scale, v.w / scale);
    int f0 = t * 4;
    Wt[(size_t)(f0 + 0) * D + d] = __float2bfloat16(d01[0] * scale);
    Wt[(size_t)(f0 + 1) * D + d] = __float2bfloat16(d01[1] * scale);
    Wt[(size_t)(f0 + 2) * D + d] = __float2bfloat16(d23[0] * scale);
    Wt[(size_t)(f0 + 3) * D + d] = __float2bfloat16(d23[1] * scale);
}

// ---------------------------------------------------------------------------
// Kernel 2: streaming X quant-dequant f32 -> bf16 (quant blocks 128 along K).
// 2 rows/block, 256 thr; thread = 4 consecutive f32 (float4 in, uint2 out).
__global__ void xqdq_kernel(const float* __restrict__ X,
                            __hip_bfloat16* __restrict__ Xdq) {
    int tid = threadIdx.x;
    size_t row = (size_t)blockIdx.x * 2 + (tid >> 7);
    int cg = tid & 127;                   // col group: 4 f32 each
    const float4 v = *reinterpret_cast<const float4*>(X + row * 512 + cg * 4);
    float am = fmaxf(fmaxf(fabsf(v.x), fabsf(v.y)), fmaxf(fabsf(v.z), fabsf(v.w)));
    am = fmaxf(am, __shfl_xor(am, 1));
    am = fmaxf(am, __shfl_xor(am, 2));
    am = fmaxf(am, __shfl_xor(am, 4));
    am = fmaxf(am, __shfl_xor(am, 8));
    am = fmaxf(am, __shfl_xor(am, 16));
    am = fmaxf(am, 1e-4f);
    float scale = am / FP8_MAX;           // exact reference scale (IEEE div)
    float inv   = FP8_MAX / am;
    floatx2 d01 = fp8_qdq2(v.x * inv, v.y * inv);
    floatx2 d23 = fp8_qdq2(v.z * inv, v.w * inv);
    uint2 o;
    o.x = f2bf(d01[0] * scale) | (f2bf(d01[1] * scale) << 16);
    o.y = f2bf(d23[0] * scale) | (f2bf(d23[1] * scale) << 16);
    *reinterpret_cast<uint2*>(Xdq + row * 512 + cg * 4) = o;
}

// ---------------------------------------------------------------------------
// Kernel 3: bf16 GEMM, BM=128/BN=128/BK=64, 256 thr = 4 waves (2x2, wave
// tile 64x64, acc 4x4 = 32 MFMA/wave/iter). Buffers: A double (2x16KB) +
// B triple (3x16KB) = 80 KB -> 2 independent blocks/CU (TLP hides drains).
// Issue per iter t: A(t+1) then B(t+2). Boundary FIFO:
// [B(t+1).4][A(t+1).4][B(t+2).4] -> vmcnt(4): t+1 landed, B(t+2) floats.
// Safety: A(t+2) DMA (issued iter t+1) overwrites buf read at iter t, but
// every iter-t A ds_read is consumed by MFMA before the barrier (lgkm
// drained by consumption). No ds_writes -> no lgkm at barriers.
// XOR slot swizzle both-sides (slot ^= row&7): 0 conflicts (rounds 3-9).
__global__ __launch_bounds__(256, 2) void gemm8(
        const __hip_bfloat16* __restrict__ Xdq,  // [M][512] bf16
        const __hip_bfloat16* __restrict__ Wt,   // [512 f][512 k] bf16
        const float* __restrict__ bias,          // [512]
        float* __restrict__ C, int M) {
    const int K = 512, N = 512;
    __shared__ char Abuf[2][16384];   // [128 r][8 slot16B] bf16
    __shared__ char Bbuf[3][16384];   // [128 f][8 slot16B] bf16

    // XCD-chunked bijective swizzle (grid 2048 % 8 == 0): the 4 tn tiles of
    // each tm are adjacent on one XCD -> A-panel L2 reuse.
    int bx   = blockIdx.x;
    int tile = (bx & 7) * (gridDim.x >> 3) + (bx >> 3);
    int tn   = tile & 3;             // N-panel of 128
    int tm   = tile >> 2;            // M-tile of 128 rows

    int tid = threadIdx.x, wid = tid >> 6, lane = tid & 63;
    int wm = wid >> 1, wn = wid & 1; // wave grid 2(M) x 2(N), tile 64x64
    int lr = lane & 15, lg = lane >> 4;

    const char* Abase = (const char*)(Xdq + (size_t)tm * 128 * K);
    const char* Bbase = (const char*)(Wt + (size_t)tn * 128 * K);
    float* Cb = C + (size_t)tm * 128 * N + tn * 128;

    floatx4 acc[4][4] = {};

    // stage one 128x64 bf16 tile (16 KB): 16 chunks of 1KB, 4 loads/thread
    auto stageA = [&](int buf, int t) {
        int kb = t * 128;
#pragma unroll
        for (int i = 0; i < 4; ++i) {
            int c = wid * 4 + i;
            int r = c * 8 + (lane >> 3);
            int s = lane & 7;
            async_copy16(Abuf[buf] + c * 1024,
                         Abase + (size_t)r * 1024 + kb + ((s ^ (r & 7)) << 4));
        }
    };
    auto stageB = [&](int buf, int t) {
        int kb = t * 128;
#pragma unroll
        for (int i = 0; i < 4; ++i) {
            int c = wid * 4 + i;
            int f = c * 8 + (lane >> 3);
            int s = lane & 7;
            async_copy16(Bbuf[buf] + c * 1024,
                         Bbase + (size_t)f * 1024 + kb + ((s ^ (f & 7)) << 4));
        }
    };

    // ---- prologue: bias.4, A0.4, B0.4, B1.4; drain to leave B1 floating --
    float bv[4];
#pragma unroll
    for (int ni = 0; ni < 4; ++ni)
        bv[ni] = bias[tn * 128 + wn * 64 + ni * 16 + lr];
    stageA(0, 0);
    stageB(0, 0);
    stageB(1, 1);
    asm volatile("s_waitcnt vmcnt(4)" ::: "memory");   // bias+A0+B0 done
    __builtin_amdgcn_s_barrier();
    __builtin_amdgcn_sched_barrier(0);

    // ---- main: 8 iters of BK=64, one barrier each ----
#pragma unroll
    for (int t = 0; t < 8; ++t) {
        const char* Ab = Abuf[t & 1];
        const char* Bb = Bbuf[t % 3];
        if (t < 7) stageA((t + 1) & 1, t + 1);
        if (t < 6) stageB((t + 2) % 3, t + 2);
        __builtin_amdgcn_s_setprio(1);
#pragma unroll
        for (int ks = 0; ks < 2; ++ks) {
            int q = (ks << 2) | lg;              // k-chunk 0..7
            bf16x8 a[4], b[4];
#pragma unroll
            for (int mi = 0; mi < 4; ++mi) {
                int r = wm * 64 + mi * 16 + lr;
                a[mi] = *reinterpret_cast<const bf16x8*>(
                    Ab + r * 128 + ((q ^ (r & 7)) << 4));
            }
#pragma unroll
            for (int ni = 0; ni < 4; ++ni) {
                int f = wn * 64 + ni * 16 + lr;
                b[ni] = *reinterpret_cast<const bf16x8*>(
                    Bb + f * 128 + ((q ^ (f & 7)) << 4));
            }
#pragma unroll
            for (int mi = 0; mi < 4; ++mi)
#pragma unroll
                for (int ni = 0; ni < 4; ++ni)
                    acc[mi][ni] = __builtin_amdgcn_mfma_f32_16x16x32_bf16(
                        a[mi], b[ni], acc[mi][ni], 0, 0, 0);
        }
        __builtin_amdgcn_s_setprio(0);
        if (t < 7) {
            // boundary: tile t+1 must be resident; newest B stage floats
            if (t < 6) asm volatile("s_waitcnt vmcnt(4)" ::: "memory");
            else       asm volatile("s_waitcnt vmcnt(0)" ::: "memory");
            __builtin_amdgcn_s_barrier();
            __builtin_amdgcn_sched_barrier(0);
        }
    }

    // ---- epilogue: C/D layout col=lane&15, row=(lane>>4)*4+e ----
#pragma unroll
    for (int ni = 0; ni < 4; ++ni) {
        int col = wn * 64 + ni * 16 + lr;
#pragma unroll
        for (int mi = 0; mi < 4; ++mi) {
            int r0 = wm * 64 + mi * 16 + lg * 4;
#pragma unroll
            for (int e = 0; e < 4; ++e)
                Cb[(size_t)(r0 + e) * N + col] = acc[mi][ni][e] + bv[ni];
        }
    }
}

// ---------------------------------------------------------------------------
extern "C" void kernel_launch(void* const* d_in, const int* in_sizes, int n_in,
                              void* d_out, int out_size, void* d_ws, size_t ws_size,
                              hipStream_t stream) {
    const float* X    = (const float*)d_in[0];
    const float* W    = (const float*)d_in[1];
    const float* bias = (const float*)d_in[2];
    const int K = 512;
    const int M = in_sizes[0] / K;   // 65536

    __hip_bfloat16* Wt  = (__hip_bfloat16*)d_ws;      // 512 KB
    __hip_bfloat16* Xdq = Wt + 512 * 512;             // 64 MB

    wdq_kernel<<<dim3(512), dim3(128), 0, stream>>>(W, Wt);
    xqdq_kernel<<<dim3(M / 2), dim3(256), 0, stream>>>(X, Xdq);
    gemm8<<<dim3((M / 128) * (512 / 128)), dim3(256), 0, stream>>>(
        Xdq, Wt, bias, (float*)d_out, M);
}